// Round 2
// baseline (665.843 us; speedup 1.0000x reference)
//
#include <hip/hip_runtime.h>

// ---------------------------------------------------------------------------
// DenseLanguageGuidanceModule on MI355X (gfx950)
// All GEMMs via bf16 hi/lo split (x3 MFMA, fp32 accumulate) for ~fp32 accuracy.
// fp32 operands (fv, fl) are split to bf16 hi/lo in-register during LDS staging.
// ---------------------------------------------------------------------------

using s16x8  = __attribute__((ext_vector_type(8))) short;
using f32x4v = __attribute__((ext_vector_type(4))) float;

__device__ __forceinline__ unsigned short f2bf(float f) {
  unsigned int u = __float_as_uint(f);
  u += 0x7fffu + ((u >> 16) & 1u);     // RNE
  return (unsigned short)(u >> 16);
}
__device__ __forceinline__ float bf2f(unsigned short h) {
  return __uint_as_float(((unsigned int)h) << 16);
}
__device__ __forceinline__ void split2(float v, unsigned short &hh, unsigned short &ll) {
  hh = f2bf(v);
  ll = f2bf(v - bf2f(hh));
}
__device__ __forceinline__ void split8(const float* __restrict__ src, s16x8& H, s16x8& L) {
  float4 v0 = *(const float4*)src;
  float4 v1 = *(const float4*)(src + 4);
  unsigned short hh, ll;
  split2(v0.x, hh, ll); H[0] = (short)hh; L[0] = (short)ll;
  split2(v0.y, hh, ll); H[1] = (short)hh; L[1] = (short)ll;
  split2(v0.z, hh, ll); H[2] = (short)hh; L[2] = (short)ll;
  split2(v0.w, hh, ll); H[3] = (short)hh; L[3] = (short)ll;
  split2(v1.x, hh, ll); H[4] = (short)hh; L[4] = (short)ll;
  split2(v1.y, hh, ll); H[5] = (short)hh; L[5] = (short)ll;
  split2(v1.z, hh, ll); H[6] = (short)hh; L[6] = (short)ll;
  split2(v1.w, hh, ll); H[7] = (short)hh; L[7] = (short)ll;
}

// transpose W[K][N] -> Wt[N][Kpad] bf16 hi/lo, zero-pad k >= K
__global__ __launch_bounds__(256) void prep_weight(const float* __restrict__ W,
                                                   unsigned short* __restrict__ Wh,
                                                   unsigned short* __restrict__ Wl,
                                                   int K, int N, int Kpad) {
  __shared__ float tile[32][33];
  int nb = blockIdx.x * 32, kb = blockIdx.y * 32;
  int tx = threadIdx.x & 31, ty = threadIdx.x >> 5;   // 32 x 8
  #pragma unroll
  for (int i = 0; i < 32; i += 8) {
    int k = kb + ty + i, n = nb + tx;
    tile[ty + i][tx] = (k < K && n < N) ? W[(long)k * N + n] : 0.f;
  }
  __syncthreads();
  #pragma unroll
  for (int i = 0; i < 32; i += 8) {
    int n = nb + ty + i, k = kb + tx;
    if (n < N && k < Kpad) {
      unsigned short hh, ll;
      split2(tile[tx][ty + i], hh, ll);
      Wh[(long)n * Kpad + k] = hh;
      Wl[(long)n * Kpad + k] = ll;
    }
  }
}

// ---------------- generic NT GEMM, bf16 hi/lo x3 ----------------
// C[m][n] = sum_k A[m][k] * Bt[n][k]
// A/Bt either pre-split bf16 hi/lo pairs, or raw fp32 (split during staging).
// Tile 128x128xBK64, 256 threads (4 waves 2x2), mfma_f32_16x16x32_bf16.
// LDS XOR-swizzle: 16B slot s of row r stored at slot (s ^ (r&7)).
struct GemmArgs {
  const unsigned short *Ah, *Alo, *Bh, *Blo;
  const float *Af, *Bf;   // fp32 sources (used when AF32 / BF32)
  int K;            // multiple of 64
  int Mld, Nld;     // clamp bounds for operand loads
  int lda, ldb;     // row strides (elements)
  long long sA, sB; // batch strides (elements)
};

template <bool AF32, bool BF32, class Epi>
__global__ __launch_bounds__(256, 2) void gemm_x3(GemmArgs g, Epi epi) {
  __shared__ __align__(16) unsigned short sm[4 * 128 * 64];   // 64 KiB
  unsigned short* sAh = sm;
  unsigned short* sAl = sm + 8192;
  unsigned short* sBh = sm + 16384;
  unsigned short* sBl = sm + 24576;

  const int t    = threadIdx.x;
  const int b    = blockIdx.z;
  const int m0   = blockIdx.y * 128;
  const int n0   = blockIdx.x * 128;
  const int lane = t & 63;
  const int w    = t >> 6;
  const int wr   = (w >> 1) * 64;
  const int wc   = (w & 1) * 64;

  const long long aBase = (long long)b * g.sA;
  const long long bBase = (long long)b * g.sB;

  f32x4v acc[4][4];
  #pragma unroll
  for (int i = 0; i < 4; ++i)
    #pragma unroll
    for (int j = 0; j < 4; ++j)
      #pragma unroll
      for (int r = 0; r < 4; ++r) acc[i][j][r] = 0.f;

  const int nkt = g.K >> 6;
  for (int kt = 0; kt < nkt; ++kt) {
    const int k0 = kt << 6;
    if (kt) __syncthreads();
    // stage A (hi/lo)
    #pragma unroll
    for (int q = 0; q < 4; ++q) {
      int flat = q * 256 + t;
      int row = flat >> 3, slot = flat & 7;
      int rg = m0 + row; if (rg > g.Mld - 1) rg = g.Mld - 1;
      int doff = row * 64 + ((slot ^ (row & 7)) << 3);
      if constexpr (AF32) {
        const float* src = g.Af + aBase + (long long)rg * g.lda + k0 + (slot << 3);
        s16x8 H, L;
        split8(src, H, L);
        *(s16x8*)&sAh[doff] = H;
        *(s16x8*)&sAl[doff] = L;
      } else {
        long long so = aBase + (long long)rg * g.lda + k0 + (slot << 3);
        *(s16x8*)&sAh[doff] = *(const s16x8*)(g.Ah + so);
        *(s16x8*)&sAl[doff] = *(const s16x8*)(g.Alo + so);
      }
    }
    // stage B (hi/lo)
    #pragma unroll
    for (int q = 0; q < 4; ++q) {
      int flat = q * 256 + t;
      int row = flat >> 3, slot = flat & 7;
      int cg = n0 + row; if (cg > g.Nld - 1) cg = g.Nld - 1;
      int doff = row * 64 + ((slot ^ (row & 7)) << 3);
      if constexpr (BF32) {
        const float* src = g.Bf + bBase + (long long)cg * g.ldb + k0 + (slot << 3);
        s16x8 H, L;
        split8(src, H, L);
        *(s16x8*)&sBh[doff] = H;
        *(s16x8*)&sBl[doff] = L;
      } else {
        long long so = bBase + (long long)cg * g.ldb + k0 + (slot << 3);
        *(s16x8*)&sBh[doff] = *(const s16x8*)(g.Bh + so);
        *(s16x8*)&sBl[doff] = *(const s16x8*)(g.Blo + so);
      }
    }
    __syncthreads();
    // compute: two 32-wide K substeps
    #pragma unroll
    for (int ks = 0; ks < 2; ++ks) {
      s16x8 ah[4], al[4], bh[4], bl[4];
      #pragma unroll
      for (int i = 0; i < 4; ++i) {
        int row  = wr + i * 16 + (lane & 15);
        int slot = ks * 4 + (lane >> 4);
        int off  = row * 64 + ((slot ^ (row & 7)) << 3);
        ah[i] = *(const s16x8*)&sAh[off];
        al[i] = *(const s16x8*)&sAl[off];
      }
      #pragma unroll
      for (int j = 0; j < 4; ++j) {
        int row  = wc + j * 16 + (lane & 15);
        int slot = ks * 4 + (lane >> 4);
        int off  = row * 64 + ((slot ^ (row & 7)) << 3);
        bh[j] = *(const s16x8*)&sBh[off];
        bl[j] = *(const s16x8*)&sBl[off];
      }
      #pragma unroll
      for (int i = 0; i < 4; ++i)
        #pragma unroll
        for (int j = 0; j < 4; ++j) {
          acc[i][j] = __builtin_amdgcn_mfma_f32_16x16x32_bf16(ah[i], bh[j], acc[i][j], 0, 0, 0);
          acc[i][j] = __builtin_amdgcn_mfma_f32_16x16x32_bf16(ah[i], bl[j], acc[i][j], 0, 0, 0);
          acc[i][j] = __builtin_amdgcn_mfma_f32_16x16x32_bf16(al[i], bh[j], acc[i][j], 0, 0, 0);
        }
    }
  }
  // epilogue: D row=(lane>>4)*4+r, col=lane&15
  #pragma unroll
  for (int i = 0; i < 4; ++i)
    #pragma unroll
    for (int j = 0; j < 4; ++j) {
      int mm = m0 + wr + i * 16 + ((lane >> 4) << 2);
      int nn = n0 + wc + j * 16 + (lane & 15);
      epi(b, mm, nn, acc[i][j]);
    }
}

// ---------------- epilogues ----------------
struct EpiBF16Pair {   // out[b][m][n] bf16 hi/lo (+optional fp32 bias)
  unsigned short *h, *lo; const float* bias; long long bs; int ld; int Mst;
  __device__ void operator()(int b, int m, int n, f32x4v v) const {
    float bb = bias ? bias[n] : 0.f;
    #pragma unroll
    for (int r = 0; r < 4; ++r) {
      int mm = m + r;
      if (mm < Mst) {
        long long o = (long long)b * bs + (long long)mm * ld + n;
        unsigned short hh, ll;
        split2(v[r] + bb, hh, ll);
        h[o] = hh; lo[o] = ll;
      }
    }
  }
};

struct EpiTransV {     // K2b: m flat = b*1024+v -> fv_vT[b][n][v], +bias
  unsigned short *h, *lo; const float* bias;
  __device__ void operator()(int, int m, int n, f32x4v v) const {
    int b2 = m >> 10, vv = m & 1023;
    float bb = bias[n];
    ushort4 H, L;
    split2(v[0] + bb, H.x, L.x); split2(v[1] + bb, H.y, L.y);
    split2(v[2] + bb, H.z, L.z); split2(v[3] + bb, H.w, L.w);
    long long o = ((long long)b2 * 512 + n) * 1024 + vv;
    *(ushort4*)(h + o)  = H;
    *(ushort4*)(lo + o) = L;
  }
};

struct EpiTransL {     // K1b: m flat = b*77+l -> fv_lT[b][n][l] (l-dim padded 128), +bias
  unsigned short *h, *lo; const float* bias;
  __device__ void operator()(int, int m, int n, f32x4v v) const {
    float bb = bias[n];
    #pragma unroll
    for (int r = 0; r < 4; ++r) {
      int mm = m + r;
      if (mm < 2464) {
        int b2 = mm / 77, l = mm - b2 * 77;
        long long o = ((long long)b2 * 512 + n) * 128 + l;
        unsigned short hh, ll;
        split2(v[r] + bb, hh, ll);
        h[o] = hh; lo[o] = ll;
      }
    }
  }
};

struct EpiScore {      // K3: a_raw[b][m][n] fp32, scaled 1/sqrt(512), m<77
  float* out;
  __device__ void operator()(int b, int m, int n, f32x4v v) const {
    #pragma unroll
    for (int r = 0; r < 4; ++r) {
      int mm = m + r;
      if (mm < 77)
        out[((long long)b * 77 + mm) * 1024 + n] = v[r] * 0.04419417382415922f;
    }
  }
};

struct EpiOut {        // K8: d_out flat [32768][768] fp32 + bias
  float* out; const float* bias;
  __device__ void operator()(int, int m, int n, f32x4v v) const {
    float bb = bias[n];
    #pragma unroll
    for (int r = 0; r < 4; ++r)
      out[(long long)(m + r) * 768 + n] = v[r] + bb;
  }
};

// ---------------- softmax over Nv (rows of a_raw) ----------------
__global__ __launch_bounds__(256) void softmax_rows(const float* __restrict__ a,
                                                    unsigned short* __restrict__ Ph,
                                                    unsigned short* __restrict__ Plo) {
  long row = blockIdx.x;                 // (b*77+l)
  const float* src = a + row * 1024;
  int t = threadIdx.x;
  float4 x = ((const float4*)src)[t];
  float mx = fmaxf(fmaxf(x.x, x.y), fmaxf(x.z, x.w));
  #pragma unroll
  for (int o = 32; o; o >>= 1) mx = fmaxf(mx, __shfl_xor(mx, o));
  __shared__ float red[4], red2[4];
  int w = t >> 6;
  if ((t & 63) == 0) red[w] = mx;
  __syncthreads();
  mx = fmaxf(fmaxf(red[0], red[1]), fmaxf(red[2], red[3]));
  float e0 = __expf(x.x - mx), e1 = __expf(x.y - mx);
  float e2 = __expf(x.z - mx), e3 = __expf(x.w - mx);
  float s = e0 + e1 + e2 + e3;
  #pragma unroll
  for (int o = 32; o; o >>= 1) s += __shfl_xor(s, o);
  if ((t & 63) == 0) red2[w] = s;
  __syncthreads();
  s = red2[0] + red2[1] + red2[2] + red2[3];
  float inv = 1.f / s;
  ushort4 H, L;
  split2(e0 * inv, H.x, L.x); split2(e1 * inv, H.y, L.y);
  split2(e2 * inv, H.z, L.z); split2(e3 * inv, H.w, L.w);
  long o = row * 1024 + (long)t * 4;
  *(ushort4*)(Ph + o)  = H;
  *(ushort4*)(Plo + o) = L;
}

// ---------------- softmax over Nl (cols), writes P2t[b][v][128] (k>=77 zero) ----
__global__ __launch_bounds__(128) void softmax_cols(const float* __restrict__ a,
                                                    unsigned short* __restrict__ Ph,
                                                    unsigned short* __restrict__ Plo) {
  __shared__ float tile[77 * 129];
  __shared__ float inv[128];
  int t = threadIdx.x;                  // 0..127
  int c = blockIdx.x;                   // v-chunk (of 128)
  int b = blockIdx.y;
  const float* src = a + (long)b * 77 * 1024 + c * 128;
  for (int r = 0; r < 77; ++r) tile[r * 129 + t] = src[(long)r * 1024 + t];
  __syncthreads();
  float mx = -1e30f;
  for (int r = 0; r < 77; ++r) mx = fmaxf(mx, tile[r * 129 + t]);
  float s = 0.f;
  for (int r = 0; r < 77; ++r) {
    float e = __expf(tile[r * 129 + t] - mx);
    tile[r * 129 + t] = e;
    s += e;
  }
  inv[t] = 1.f / s;
  __syncthreads();
  unsigned short* dh = Ph  + ((long)b * 1024 + c * 128) * 128;
  unsigned short* dl = Plo + ((long)b * 1024 + c * 128) * 128;
  for (int vb = 0; vb < 128; vb += 2) {
    int v = vb + (t >> 6);
    int k = (t & 63) * 2;
    float iv = inv[v];
    float p0 = (k     < 77) ? tile[k * 129 + v] * iv       : 0.f;
    float p1 = (k + 1 < 77) ? tile[(k + 1) * 129 + v] * iv : 0.f;
    ushort2 H, L;
    split2(p0, H.x, L.x); split2(p1, H.y, L.y);
    *(ushort2*)(dh + (long)v * 128 + k) = H;
    *(ushort2*)(dl + (long)v * 128 + k) = L;
  }
}

// ---------------------------------------------------------------------------
extern "C" void kernel_launch(void* const* d_in, const int* in_sizes, int n_in,
                              void* d_out, int out_size, void* d_ws, size_t ws_size,
                              hipStream_t stream) {
  const float* fv   = (const float*)d_in[0];
  const float* fl   = (const float*)d_in[1];
  const float* W_vk = (const float*)d_in[2];
  const float* b_vk = (const float*)d_in[3];
  const float* W_vv = (const float*)d_in[4];
  const float* b_vv = (const float*)d_in[5];
  const float* W_lk = (const float*)d_in[6];
  const float* b_lk = (const float*)d_in[7];
  const float* W_lv = (const float*)d_in[8];
  const float* b_lv = (const float*)d_in[9];
  const float* W_m  = (const float*)d_in[10];
  const float* b_m  = (const float*)d_in[11];

  char* base = (char*)d_ws;
  size_t off = 0;
  auto take = [&](size_t bytes) -> char* {
    char* p = base + off;
    off = (off + bytes + 255) & ~(size_t)255;
    return p;
  };

  // weights (persistent)
  unsigned short* wvk_h = (unsigned short*)take(786432);
  unsigned short* wvk_l = (unsigned short*)take(786432);
  unsigned short* wvv_h = (unsigned short*)take(786432);
  unsigned short* wvv_l = (unsigned short*)take(786432);
  unsigned short* wlk_h = (unsigned short*)take(524288);
  unsigned short* wlk_l = (unsigned short*)take(524288);
  unsigned short* wlv_h = (unsigned short*)take(524288);
  unsigned short* wlv_l = (unsigned short*)take(524288);
  unsigned short* wm_h  = (unsigned short*)take(196608);
  unsigned short* wm_l  = (unsigned short*)take(196608);
  // persistent small intermediates
  unsigned short* fkl_h   = (unsigned short*)take(2523136);
  unsigned short* fkl_lo  = (unsigned short*)take(2523136);
  unsigned short* fvlT_h  = (unsigned short*)take(4194304);
  unsigned short* fvlT_lo = (unsigned short*)take(4194304);
  // Region B: fk_v hi/lo (dead after K3) | P1 + P2t (written K4a/K4b)
  char* regB = take(67108864);
  unsigned short* fkv_h  = (unsigned short*)regB;
  unsigned short* fkv_lo = (unsigned short*)(regB + 33554432);
  unsigned short* p1_h   = (unsigned short*)regB;
  unsigned short* p1_lo  = (unsigned short*)(regB + 5046272);
  unsigned short* p2t_h  = (unsigned short*)(regB + 10092544);
  unsigned short* p2t_lo = (unsigned short*)(regB + 18481152);
  // Region C: fv_vT hi/lo (dead after K5) | fa_l (K6) ; + fm (K7)
  char* regC = take(83886080);
  unsigned short* fvvT_h  = (unsigned short*)regC;
  unsigned short* fvvT_lo = (unsigned short*)(regC + 33554432);
  unsigned short* fal_h   = (unsigned short*)regC;
  unsigned short* fal_lo  = (unsigned short*)(regC + 33554432);
  unsigned short* fm_h    = (unsigned short*)(regC + 67108864);
  unsigned short* fm_lo   = (unsigned short*)(regC + 75497472);
  // Region D: a_raw (dead after softmaxes) | fa_v (written K5)
  char* regD = take(10092544);
  float*          araw   = (float*)regD;
  unsigned short* fav_h  = (unsigned short*)regD;
  unsigned short* fav_lo = (unsigned short*)(regD + 4194304);

  if (off > ws_size) return;  // workspace too small: fail loudly via mismatch

  // ---- prep weights ----
  prep_weight<<<dim3(16, 24), 256, 0, stream>>>(W_vk, wvk_h, wvk_l, 768, 512, 768);
  prep_weight<<<dim3(16, 24), 256, 0, stream>>>(W_vv, wvv_h, wvv_l, 768, 512, 768);
  prep_weight<<<dim3(16, 16), 256, 0, stream>>>(W_lk, wlk_h, wlk_l, 512, 512, 512);
  prep_weight<<<dim3(16, 16), 256, 0, stream>>>(W_lv, wlv_h, wlv_l, 512, 512, 512);
  prep_weight<<<dim3(24, 4), 256, 0, stream>>>(W_m, wm_h, wm_l, 77, 768, 128);

  // ---- K1a: fk_l = fl @ W_lk + b_lk  [2464 x 512] ----
  {
    GemmArgs g{}; g.Af = fl; g.Bh = wlk_h; g.Blo = wlk_l;
    g.K = 512; g.Mld = 2464; g.Nld = 512; g.lda = 512; g.ldb = 512; g.sA = 0; g.sB = 0;
    EpiBF16Pair e{fkl_h, fkl_lo, b_lk, 0, 512, 2464};
    gemm_x3<true, false, EpiBF16Pair><<<dim3(4, 20, 1), 256, 0, stream>>>(g, e);
  }
  // ---- K1b: fv_lT[b][d][l] = (fl @ W_lv + b_lv)^T ----
  {
    GemmArgs g{}; g.Af = fl; g.Bh = wlv_h; g.Blo = wlv_l;
    g.K = 512; g.Mld = 2464; g.Nld = 512; g.lda = 512; g.ldb = 512; g.sA = 0; g.sB = 0;
    EpiTransL e{fvlT_h, fvlT_lo, b_lv};
    gemm_x3<true, false, EpiTransL><<<dim3(4, 20, 1), 256, 0, stream>>>(g, e);
  }
  // ---- K2a: fk_v = fv @ W_vk + b_vk  [32768 x 512] ----
  {
    GemmArgs g{}; g.Af = fv; g.Bh = wvk_h; g.Blo = wvk_l;
    g.K = 768; g.Mld = 32768; g.Nld = 512; g.lda = 768; g.ldb = 768; g.sA = 0; g.sB = 0;
    EpiBF16Pair e{fkv_h, fkv_lo, b_vk, 0, 512, 32768};
    gemm_x3<true, false, EpiBF16Pair><<<dim3(4, 256, 1), 256, 0, stream>>>(g, e);
  }
  // ---- K2b: fv_vT[b][d][v] = (fv @ W_vv + b_vv)^T ----
  {
    GemmArgs g{}; g.Af = fv; g.Bh = wvv_h; g.Blo = wvv_l;
    g.K = 768; g.Mld = 32768; g.Nld = 512; g.lda = 768; g.ldb = 768; g.sA = 0; g.sB = 0;
    EpiTransV e{fvvT_h, fvvT_lo, b_vv};
    gemm_x3<true, false, EpiTransV><<<dim3(4, 256, 1), 256, 0, stream>>>(g, e);
  }
  // ---- K3: a_raw[b][l][v] = fk_l . fk_v / sqrt(512) ----
  {
    GemmArgs g{}; g.Ah = fkl_h; g.Alo = fkl_lo; g.Bh = fkv_h; g.Blo = fkv_lo;
    g.K = 512; g.Mld = 77; g.Nld = 1024; g.lda = 512; g.ldb = 512;
    g.sA = 77 * 512; g.sB = 1024 * 512;
    EpiScore e{araw};
    gemm_x3<false, false, EpiScore><<<dim3(8, 1, 32), 256, 0, stream>>>(g, e);
  }
  // ---- softmaxes ----
  softmax_rows<<<2464, 256, 0, stream>>>(araw, p1_h, p1_lo);
  softmax_cols<<<dim3(8, 32), 128, 0, stream>>>(araw, p2t_h, p2t_lo);
  // ---- K5: fa_v[b][l][e] = P1 @ fv_v  (via fv_vT) ----
  {
    GemmArgs g{}; g.Ah = p1_h; g.Alo = p1_lo; g.Bh = fvvT_h; g.Blo = fvvT_lo;
    g.K = 1024; g.Mld = 77; g.Nld = 512; g.lda = 1024; g.ldb = 1024;
    g.sA = 77 * 1024; g.sB = 512 * 1024;
    EpiBF16Pair e{fav_h, fav_lo, nullptr, 128 * 512, 512, 128};
    gemm_x3<false, false, EpiBF16Pair><<<dim3(4, 1, 32), 256, 0, stream>>>(g, e);
  }
  // ---- K6: fa_l[b][v][e] = P2t @ fv_l (via fv_lT), K padded to 128 ----
  {
    GemmArgs g{}; g.Ah = p2t_h; g.Alo = p2t_lo; g.Bh = fvlT_h; g.Blo = fvlT_lo;
    g.K = 128; g.Mld = 1024; g.Nld = 512; g.lda = 128; g.ldb = 128;
    g.sA = 1024 * 128; g.sB = 512 * 128;
    EpiBF16Pair e{fal_h, fal_lo, nullptr, 1024 * 512, 512, 1024};
    gemm_x3<false, false, EpiBF16Pair><<<dim3(4, 8, 32), 256, 0, stream>>>(g, e);
  }
  // ---- K7: fm[b][v][l] = fa_l . fa_v  (N padded to 128) ----
  {
    GemmArgs g{}; g.Ah = fal_h; g.Alo = fal_lo; g.Bh = fav_h; g.Blo = fav_lo;
    g.K = 512; g.Mld = 1024; g.Nld = 128; g.lda = 512; g.ldb = 512;
    g.sA = 1024 * 512; g.sB = 128 * 512;
    EpiBF16Pair e{fm_h, fm_lo, nullptr, 1024 * 128, 128, 1024};
    gemm_x3<false, false, EpiBF16Pair><<<dim3(1, 8, 32), 256, 0, stream>>>(g, e);
  }
  // ---- K8: out = fm @ W_m + b_m  [32768 x 768], K=128 (zero-padded W_m^T) ----
  {
    GemmArgs g{}; g.Ah = fm_h; g.Alo = fm_lo; g.Bh = wm_h; g.Blo = wm_l;
    g.K = 128; g.Mld = 32768; g.Nld = 768; g.lda = 128; g.ldb = 128; g.sA = 0; g.sB = 0;
    EpiOut e{(float*)d_out, b_m};
    gemm_x3<false, false, EpiOut><<<dim3(6, 256, 1), 256, 0, stream>>>(g, e);
  }
  (void)in_sizes; (void)n_in; (void)out_size;
}

// Round 4
// 590.998 us; speedup vs baseline: 1.1266x; 1.1266x over previous
//
#include <hip/hip_runtime.h>

// ---------------------------------------------------------------------------
// DenseLanguageGuidanceModule on MI355X (gfx950)
// bf16 hi/lo split GEMMs (x3 MFMA, fp32 accumulate) for ~fp32 accuracy.
// Round 4 (= round 3 resubmit; infra failure): 2-phase double-buffered K-loop
// (BK=32), fused projections, algebraic removal of fm/fa_l
// (out = P2t @ ((fv_l@fa_v^T)@W_m)).
// ---------------------------------------------------------------------------

using s16x8  = __attribute__((ext_vector_type(8))) short;
using f32x4v = __attribute__((ext_vector_type(4))) float;

__device__ __forceinline__ unsigned short f2bf(float f) {
  unsigned int u = __float_as_uint(f);
  u += 0x7fffu + ((u >> 16) & 1u);     // RNE
  return (unsigned short)(u >> 16);
}
__device__ __forceinline__ float bf2f(unsigned short h) {
  return __uint_as_float(((unsigned int)h) << 16);
}
__device__ __forceinline__ void split2(float v, unsigned short &hh, unsigned short &ll) {
  hh = f2bf(v);
  ll = f2bf(v - bf2f(hh));
}
__device__ __forceinline__ void split8v(float4 a, float4 b, s16x8& H, s16x8& L) {
  unsigned short hh, ll;
  split2(a.x, hh, ll); H[0] = (short)hh; L[0] = (short)ll;
  split2(a.y, hh, ll); H[1] = (short)hh; L[1] = (short)ll;
  split2(a.z, hh, ll); H[2] = (short)hh; L[2] = (short)ll;
  split2(a.w, hh, ll); H[3] = (short)hh; L[3] = (short)ll;
  split2(b.x, hh, ll); H[4] = (short)hh; L[4] = (short)ll;
  split2(b.y, hh, ll); H[5] = (short)hh; L[5] = (short)ll;
  split2(b.z, hh, ll); H[6] = (short)hh; L[6] = (short)ll;
  split2(b.w, hh, ll); H[7] = (short)hh; L[7] = (short)ll;
}

// transpose W[K][N] -> Wt[N][Kpad] bf16 hi/lo, zero-pad k >= K
__global__ __launch_bounds__(256) void prep_weight(const float* __restrict__ W,
                                                   unsigned short* __restrict__ Wh,
                                                   unsigned short* __restrict__ Wl,
                                                   int K, int N, int Kpad) {
  __shared__ float tile[32][33];
  int nb = blockIdx.x * 32, kb = blockIdx.y * 32;
  int tx = threadIdx.x & 31, ty = threadIdx.x >> 5;   // 32 x 8
  #pragma unroll
  for (int i = 0; i < 32; i += 8) {
    int k = kb + ty + i, n = nb + tx;
    tile[ty + i][tx] = (k < K && n < N) ? W[(long)k * N + n] : 0.f;
  }
  __syncthreads();
  #pragma unroll
  for (int i = 0; i < 32; i += 8) {
    int n = nb + ty + i, k = kb + tx;
    if (n < N && k < Kpad) {
      unsigned short hh, ll;
      split2(tile[tx][ty + i], hh, ll);
      Wh[(long)n * Kpad + k] = hh;
      Wl[(long)n * Kpad + k] = ll;
    }
  }
}

// ---------------- generic NT GEMM, bf16 hi/lo x3, 2-phase dbuf ----------------
// C[m][n] = sum_k A[m][k] * Bt[n][k]
// A: pre-split bf16 pair, or raw fp32 (split in-register during staging).
// Tile 128x128, BK=32, 256 threads (4 waves 2x2, wave=64x64 as 4x4 16x16x32).
// LDS: 2 bufs x (Apair 16KB + Bpair 16KB) = 64KB. Swizzle: chunk c' = c ^ ((r>>1)&3).
struct GemmArgs {
  const unsigned short *Ah, *Alo, *Bh, *Blo;
  const float *Af;  // fp32 A source (when AF32)
  int K;            // multiple of 32
  int Mld, Nld;     // row clamp bounds (per-batch when m0/n0 are 0)
  int lda, ldb;     // row strides (elements)
  long long sA, sB; // batch strides (elements)
};

template <bool AF32, class Epi>
__global__ __launch_bounds__(256, 2) void gemm2(GemmArgs g, Epi epi) {
  // shorts: buf p at p*16384; Ah +0, Al +4096, Bh +8192, Bl +12288
  __shared__ __align__(16) unsigned short sm[32768];

  const int t    = threadIdx.x;
  const int b    = blockIdx.z;
  const int m0   = blockIdx.y * 128;
  const int n0   = blockIdx.x * 128;
  const int lane = t & 63;
  const int w    = t >> 6;
  const int wr   = (w >> 1) * 64;
  const int wc   = (w & 1) * 64;

  const long long aBase = (long long)b * g.sA;
  const long long bBase = (long long)b * g.sB;

  // staging coords: two chunks per thread per component (q=0,1)
  const int rA0 = t >> 2, rA1 = 64 + (t >> 2), cc = t & 3;
  const int cOff = cc << 3;
  int mr0 = m0 + rA0; if (mr0 > g.Mld - 1) mr0 = g.Mld - 1;
  int mr1 = m0 + rA1; if (mr1 > g.Mld - 1) mr1 = g.Mld - 1;
  int nr0 = n0 + rA0; if (nr0 > g.Nld - 1) nr0 = g.Nld - 1;
  int nr1 = n0 + rA1; if (nr1 > g.Nld - 1) nr1 = g.Nld - 1;
  const long long aR0 = aBase + (long long)mr0 * g.lda;
  const long long aR1 = aBase + (long long)mr1 * g.lda;
  const long long bR0 = bBase + (long long)nr0 * g.ldb;
  const long long bR1 = bBase + (long long)nr1 * g.ldb;
  const int wA0 = rA0 * 32 + ((cc ^ ((rA0 >> 1) & 3)) << 3);
  const int wA1 = rA1 * 32 + ((cc ^ ((rA1 >> 1) & 3)) << 3);

  // read-fragment offsets (constant; add buf base)
  int roffA[4], roffB[4];
  #pragma unroll
  for (int i = 0; i < 4; ++i) {
    int row = wr + i * 16 + (lane & 15);
    int ch  = lane >> 4;
    roffA[i] = row * 32 + ((ch ^ ((row >> 1) & 3)) << 3);
    row = wc + i * 16 + (lane & 15);
    roffB[i] = row * 32 + ((ch ^ ((row >> 1) & 3)) << 3);
  }

  f32x4v acc[4][4];
  #pragma unroll
  for (int i = 0; i < 4; ++i)
    #pragma unroll
    for (int j = 0; j < 4; ++j)
      #pragma unroll
      for (int r = 0; r < 4; ++r) acc[i][j][r] = 0.f;

  float4 pa0, pa1, pa2, pa3;   // AF32 prefetch
  s16x8 pah0, pah1, pal0, pal1;
  s16x8 pbh0, pbh1, pbl0, pbl1;

  auto issueLoads = [&](int k0) {
    if constexpr (AF32) {
      const float* s0 = g.Af + (aR0 + k0 + cOff);
      const float* s1 = g.Af + (aR1 + k0 + cOff);
      pa0 = *(const float4*)s0; pa1 = *(const float4*)(s0 + 4);
      pa2 = *(const float4*)s1; pa3 = *(const float4*)(s1 + 4);
    } else {
      pah0 = *(const s16x8*)(g.Ah  + (aR0 + k0 + cOff));
      pah1 = *(const s16x8*)(g.Ah  + (aR1 + k0 + cOff));
      pal0 = *(const s16x8*)(g.Alo + (aR0 + k0 + cOff));
      pal1 = *(const s16x8*)(g.Alo + (aR1 + k0 + cOff));
    }
    pbh0 = *(const s16x8*)(g.Bh  + (bR0 + k0 + cOff));
    pbh1 = *(const s16x8*)(g.Bh  + (bR1 + k0 + cOff));
    pbl0 = *(const s16x8*)(g.Blo + (bR0 + k0 + cOff));
    pbl1 = *(const s16x8*)(g.Blo + (bR1 + k0 + cOff));
  };
  auto writeStage = [&](int p) {
    unsigned short* base = sm + p * 16384;
    if constexpr (AF32) {
      s16x8 H, L;
      split8v(pa0, pa1, H, L);
      *(s16x8*)(base + wA0) = H; *(s16x8*)(base + 4096 + wA0) = L;
      split8v(pa2, pa3, H, L);
      *(s16x8*)(base + wA1) = H; *(s16x8*)(base + 4096 + wA1) = L;
    } else {
      *(s16x8*)(base + wA0) = pah0; *(s16x8*)(base + wA1) = pah1;
      *(s16x8*)(base + 4096 + wA0) = pal0; *(s16x8*)(base + 4096 + wA1) = pal1;
    }
    *(s16x8*)(base + 8192  + wA0) = pbh0; *(s16x8*)(base + 8192  + wA1) = pbh1;
    *(s16x8*)(base + 12288 + wA0) = pbl0; *(s16x8*)(base + 12288 + wA1) = pbl1;
  };

  issueLoads(0);
  writeStage(0);
  int p = 0;
  const int nkt = g.K >> 5;
  for (int kt = 0; kt < nkt; ++kt) {
    __syncthreads();                       // buf[p] now visible to all waves
    if (kt + 1 < nkt) issueLoads((kt + 1) << 5);   // in flight under compute
    unsigned short* base = sm + p * 16384;
    s16x8 ah[4], al[4], bh[4], bl[4];
    #pragma unroll
    for (int i = 0; i < 4; ++i) {
      ah[i] = *(const s16x8*)(base + roffA[i]);
      al[i] = *(const s16x8*)(base + 4096 + roffA[i]);
    }
    #pragma unroll
    for (int j = 0; j < 4; ++j) {
      bh[j] = *(const s16x8*)(base + 8192  + roffB[j]);
      bl[j] = *(const s16x8*)(base + 12288 + roffB[j]);
    }
    #pragma unroll
    for (int i = 0; i < 4; ++i)
      #pragma unroll
      for (int j = 0; j < 4; ++j) {
        acc[i][j] = __builtin_amdgcn_mfma_f32_16x16x32_bf16(ah[i], bh[j], acc[i][j], 0, 0, 0);
        acc[i][j] = __builtin_amdgcn_mfma_f32_16x16x32_bf16(ah[i], bl[j], acc[i][j], 0, 0, 0);
        acc[i][j] = __builtin_amdgcn_mfma_f32_16x16x32_bf16(al[i], bh[j], acc[i][j], 0, 0, 0);
      }
    if (kt + 1 < nkt) writeStage(p ^ 1);   // regs arrived during compute
    p ^= 1;
  }
  // epilogue: D row=(lane>>4)*4+r, col=lane&15
  #pragma unroll
  for (int i = 0; i < 4; ++i)
    #pragma unroll
    for (int j = 0; j < 4; ++j) {
      int mm = m0 + wr + i * 16 + ((lane >> 4) << 2);
      int nn = n0 + wc + j * 16 + (lane & 15);
      epi(b, mm, nn, acc[i][j]);
    }
}

// ---------------- epilogues ----------------
struct EpiBF16Pair {   // out[b][m][n] bf16 hi/lo pair (+optional bias)
  unsigned short *h, *lo; const float* bias; long long bs; int ld; int Mst;
  __device__ void operator()(int b, int m, int n, f32x4v v) const {
    float bb = bias ? bias[n] : 0.f;
    #pragma unroll
    for (int r = 0; r < 4; ++r) {
      int mm = m + r;
      if (mm < Mst) {
        long long o = (long long)b * bs + (long long)mm * ld + n;
        unsigned short hh, ll;
        split2(v[r] + bb, hh, ll);
        h[o] = hh; lo[o] = ll;
      }
    }
  }
};

struct EpiDualL {      // K1f: n<512 -> fkl[m][n]; n>=512 -> fvl[m][n-512]
  unsigned short *kh, *kl, *vh, *vl; const float *bk, *bv;
  __device__ void operator()(int, int m, int n, f32x4v v) const {
    bool lo512 = n < 512;
    float bb = lo512 ? bk[n] : bv[n - 512];
    int nn = lo512 ? n : n - 512;
    unsigned short* H = lo512 ? kh : vh;
    unsigned short* L = lo512 ? kl : vl;
    #pragma unroll
    for (int r = 0; r < 4; ++r) {
      int mm = m + r;
      if (mm < 2464) {
        long long o = (long long)mm * 512 + nn;
        unsigned short hh, ll;
        split2(v[r] + bb, hh, ll);
        H[o] = hh; L[o] = ll;
      }
    }
  }
};

struct EpiDualV {      // K2f: n<512 -> fkv[m][n]; n>=512 -> fvvT[b2][n-512][v]
  unsigned short *kh, *kl, *vh, *vl; const float *bk, *bv;
  __device__ void operator()(int, int m, int n, f32x4v v) const {
    if (n < 512) {
      float bb = bk[n];
      #pragma unroll
      for (int r = 0; r < 4; ++r) {
        long long o = (long long)(m + r) * 512 + n;
        unsigned short hh, ll;
        split2(v[r] + bb, hh, ll);
        kh[o] = hh; kl[o] = ll;
      }
    } else {
      int b2 = m >> 10, vv = m & 1023;
      float bb = bv[n - 512];
      ushort4 H, L;
      split2(v[0] + bb, H.x, L.x); split2(v[1] + bb, H.y, L.y);
      split2(v[2] + bb, H.z, L.z); split2(v[3] + bb, H.w, L.w);
      long long o = ((long long)b2 * 512 + (n - 512)) * 1024 + vv;
      *(ushort4*)(vh + o) = H;
      *(ushort4*)(vl + o) = L;
    }
  }
};

struct EpiScore {      // K3: a_raw[b][m][n] fp32, scaled, m<77
  float* out;
  __device__ void operator()(int b, int m, int n, f32x4v v) const {
    #pragma unroll
    for (int r = 0; r < 4; ++r) {
      int mm = m + r;
      if (mm < 77)
        out[((long long)b * 77 + mm) * 1024 + n] = v[r] * 0.04419417382415922f;
    }
  }
};

struct EpiTransT {     // T-gemm: T_t[b][o=n][l=m+r], zero l>=77
  unsigned short *h, *lo;
  __device__ void operator()(int b, int m, int n, f32x4v v) const {
    #pragma unroll
    for (int r = 0; r < 4; ++r) {
      int mm = m + r;
      float val = (mm < 77) ? v[r] : 0.f;
      long long o = (long long)b * 98304 + (long long)n * 128 + mm;
      unsigned short hh, ll;
      split2(val, hh, ll);
      h[o] = hh; lo[o] = ll;
    }
  }
};

struct EpiOutB {       // OUT: d_out[b*1024+m][768] fp32 + b_m
  float* out; const float* bias;
  __device__ void operator()(int b, int m, int n, f32x4v v) const {
    float bb = bias[n];
    #pragma unroll
    for (int r = 0; r < 4; ++r)
      out[(long long)(b * 1024 + m + r) * 768 + n] = v[r] + bb;
  }
};

// ---------------- softmax over Nv (rows of a_raw) ----------------
__global__ __launch_bounds__(256) void softmax_rows(const float* __restrict__ a,
                                                    unsigned short* __restrict__ Ph,
                                                    unsigned short* __restrict__ Plo) {
  long row = blockIdx.x;                 // (b*77+l)
  const float* src = a + row * 1024;
  int t = threadIdx.x;
  float4 x = ((const float4*)src)[t];
  float mx = fmaxf(fmaxf(x.x, x.y), fmaxf(x.z, x.w));
  #pragma unroll
  for (int o = 32; o; o >>= 1) mx = fmaxf(mx, __shfl_xor(mx, o));
  __shared__ float red[4], red2[4];
  int w = t >> 6;
  if ((t & 63) == 0) red[w] = mx;
  __syncthreads();
  mx = fmaxf(fmaxf(red[0], red[1]), fmaxf(red[2], red[3]));
  float e0 = __expf(x.x - mx), e1 = __expf(x.y - mx);
  float e2 = __expf(x.z - mx), e3 = __expf(x.w - mx);
  float s = e0 + e1 + e2 + e3;
  #pragma unroll
  for (int o = 32; o; o >>= 1) s += __shfl_xor(s, o);
  if ((t & 63) == 0) red2[w] = s;
  __syncthreads();
  s = red2[0] + red2[1] + red2[2] + red2[3];
  float inv = 1.f / s;
  ushort4 H, L;
  split2(e0 * inv, H.x, L.x); split2(e1 * inv, H.y, L.y);
  split2(e2 * inv, H.z, L.z); split2(e3 * inv, H.w, L.w);
  long o = row * 1024 + (long)t * 4;
  *(ushort4*)(Ph + o)  = H;
  *(ushort4*)(Plo + o) = L;
}

// -------- softmax over Nl (cols), writes P2t[b][v][128] (k>=77 zero) --------
__global__ __launch_bounds__(128) void softmax_cols(const float* __restrict__ a,
                                                    unsigned short* __restrict__ Ph,
                                                    unsigned short* __restrict__ Plo) {
  __shared__ float tile[77 * 129];
  __shared__ float inv[128];
  int t = threadIdx.x;                  // 0..127
  int c = blockIdx.x;                   // v-chunk (of 128)
  int b = blockIdx.y;
  const float* src = a + (long)b * 77 * 1024 + c * 128;
  for (int r = 0; r < 77; ++r) tile[r * 129 + t] = src[(long)r * 1024 + t];
  __syncthreads();
  float mx = -1e30f;
  for (int r = 0; r < 77; ++r) mx = fmaxf(mx, tile[r * 129 + t]);
  float s = 0.f;
  for (int r = 0; r < 77; ++r) {
    float e = __expf(tile[r * 129 + t] - mx);
    tile[r * 129 + t] = e;
    s += e;
  }
  inv[t] = 1.f / s;
  __syncthreads();
  unsigned short* dh = Ph  + ((long)b * 1024 + c * 128) * 128;
  unsigned short* dl = Plo + ((long)b * 1024 + c * 128) * 128;
  for (int vb = 0; vb < 128; vb += 2) {
    int v = vb + (t >> 6);
    int k = (t & 63) * 2;
    float iv = inv[v];
    float p0 = (k     < 77) ? tile[k * 129 + v] * iv       : 0.f;
    float p1 = (k + 1 < 77) ? tile[(k + 1) * 129 + v] * iv : 0.f;
    ushort2 H, L;
    split2(p0, H.x, L.x); split2(p1, H.y, L.y);
    *(ushort2*)(dh + (long)v * 128 + k) = H;
    *(ushort2*)(dl + (long)v * 128 + k) = L;
  }
}

// ---------------------------------------------------------------------------
extern "C" void kernel_launch(void* const* d_in, const int* in_sizes, int n_in,
                              void* d_out, int out_size, void* d_ws, size_t ws_size,
                              hipStream_t stream) {
  const float* fv   = (const float*)d_in[0];
  const float* fl   = (const float*)d_in[1];
  const float* W_vk = (const float*)d_in[2];
  const float* b_vk = (const float*)d_in[3];
  const float* W_vv = (const float*)d_in[4];
  const float* b_vv = (const float*)d_in[5];
  const float* W_lk = (const float*)d_in[6];
  const float* b_lk = (const float*)d_in[7];
  const float* W_lv = (const float*)d_in[8];
  const float* b_lv = (const float*)d_in[9];
  const float* W_m  = (const float*)d_in[10];
  const float* b_m  = (const float*)d_in[11];

  char* base = (char*)d_ws;
  size_t off = 0;
  auto take = [&](size_t bytes) -> char* {
    char* p = base + off;
    off = (off + bytes + 255) & ~(size_t)255;
    return p;
  };

  // weights (concatenated, pre-transposed, bf16 pairs)
  unsigned short* wcatv_h = (unsigned short*)take(1572864);  // [1024][768]
  unsigned short* wcatv_l = (unsigned short*)take(1572864);
  unsigned short* wcatl_h = (unsigned short*)take(1048576);  // [1024][512]
  unsigned short* wcatl_l = (unsigned short*)take(1048576);
  unsigned short* wm_h    = (unsigned short*)take(196608);   // [768][128]
  unsigned short* wm_l    = (unsigned short*)take(196608);
  // intermediates
  unsigned short* fkl_h  = (unsigned short*)take(2523136);   // [2464][512]
  unsigned short* fkl_l  = (unsigned short*)take(2523136);
  unsigned short* fvl_h  = (unsigned short*)take(2523136);   // [2464][512]
  unsigned short* fvl_l  = (unsigned short*)take(2523136);
  unsigned short* fkv_h  = (unsigned short*)take(33554432);  // [32768][512]
  unsigned short* fkv_l  = (unsigned short*)take(33554432);
  unsigned short* fvvT_h = (unsigned short*)take(33554432);  // [32][512][1024]
  unsigned short* fvvT_l = (unsigned short*)take(33554432);
  float*          araw   = (float*)take(10092544);           // [32][77][1024]
  unsigned short* p1_h   = (unsigned short*)take(5046272);   // [2464][1024]
  unsigned short* p1_l   = (unsigned short*)take(5046272);
  unsigned short* p2t_h  = (unsigned short*)take(8388608);   // [32][1024][128]
  unsigned short* p2t_l  = (unsigned short*)take(8388608);
  unsigned short* fav_h  = (unsigned short*)take(4194304);   // [32][128][512]
  unsigned short* fav_l  = (unsigned short*)take(4194304);
  unsigned short* s_h    = (unsigned short*)take(1048576);   // [32][128][128]
  unsigned short* s_l    = (unsigned short*)take(1048576);
  unsigned short* tt_h   = (unsigned short*)take(6291456);   // [32][768][128]
  unsigned short* tt_l   = (unsigned short*)take(6291456);

  if (off > ws_size) return;  // workspace too small: fail loudly via mismatch

  // ---- prep weights ----
  prep_weight<<<dim3(16, 24), 256, 0, stream>>>(W_vk, wcatv_h, wcatv_l, 768, 512, 768);
  prep_weight<<<dim3(16, 24), 256, 0, stream>>>(W_vv, wcatv_h + 512 * 768, wcatv_l + 512 * 768, 768, 512, 768);
  prep_weight<<<dim3(16, 16), 256, 0, stream>>>(W_lk, wcatl_h, wcatl_l, 512, 512, 512);
  prep_weight<<<dim3(16, 16), 256, 0, stream>>>(W_lv, wcatl_h + 512 * 512, wcatl_l + 512 * 512, 512, 512, 512);
  prep_weight<<<dim3(24, 4), 256, 0, stream>>>(W_m, wm_h, wm_l, 77, 768, 128);

  // ---- K1f: [fk_l | fv_l] = fl @ [W_lk | W_lv] + bias  (M=2464, N=1024, K=512)
  {
    GemmArgs g{}; g.Af = fl; g.Bh = wcatl_h; g.Blo = wcatl_l;
    g.K = 512; g.Mld = 2464; g.Nld = 1024; g.lda = 512; g.ldb = 512; g.sA = 0; g.sB = 0;
    EpiDualL e{fkl_h, fkl_l, fvl_h, fvl_l, b_lk, b_lv};
    gemm2<true, EpiDualL><<<dim3(8, 20, 1), 256, 0, stream>>>(g, e);
  }
  // ---- K2f: [fk_v | fv_v^T] = fv @ [W_vk | W_vv] + bias (M=32768, N=1024, K=768)
  {
    GemmArgs g{}; g.Af = fv; g.Bh = wcatv_h; g.Blo = wcatv_l;
    g.K = 768; g.Mld = 32768; g.Nld = 1024; g.lda = 768; g.ldb = 768; g.sA = 0; g.sB = 0;
    EpiDualV e{fkv_h, fkv_l, fvvT_h, fvvT_l, b_vk, b_vv};
    gemm2<true, EpiDualV><<<dim3(8, 256, 1), 256, 0, stream>>>(g, e);
  }
  // ---- K3: a_raw[b][l][v] = fk_l . fk_v / sqrt(512) ----
  {
    GemmArgs g{}; g.Ah = fkl_h; g.Alo = fkl_l; g.Bh = fkv_h; g.Blo = fkv_l;
    g.K = 512; g.Mld = 77; g.Nld = 1024; g.lda = 512; g.ldb = 512;
    g.sA = 77 * 512; g.sB = 1024 * 512;
    EpiScore e{araw};
    gemm2<false, EpiScore><<<dim3(8, 1, 32), 256, 0, stream>>>(g, e);
  }
  // ---- softmaxes ----
  softmax_rows<<<2464, 256, 0, stream>>>(araw, p1_h, p1_l);
  softmax_cols<<<dim3(8, 32), 128, 0, stream>>>(araw, p2t_h, p2t_l);
  // ---- K5: fa_v[b][l][e] = P1 @ fv_v (via fv_vT)  (M=77p128, N=512, K=1024)
  {
    GemmArgs g{}; g.Ah = p1_h; g.Alo = p1_l; g.Bh = fvvT_h; g.Blo = fvvT_l;
    g.K = 1024; g.Mld = 77; g.Nld = 512; g.lda = 1024; g.ldb = 1024;
    g.sA = 77 * 1024; g.sB = 512 * 1024;
    EpiBF16Pair e{fav_h, fav_l, nullptr, 128 * 512, 512, 128};
    gemm2<false, EpiBF16Pair><<<dim3(4, 1, 32), 256, 0, stream>>>(g, e);
  }
  // ---- S[b][l'][l] = fv_l . fa_v  (M=77p128, N=128, K=512)
  {
    GemmArgs g{}; g.Ah = fvl_h; g.Alo = fvl_l; g.Bh = fav_h; g.Blo = fav_l;
    g.K = 512; g.Mld = 77; g.Nld = 128; g.lda = 512; g.ldb = 512;
    g.sA = 77 * 512; g.sB = 128 * 512;
    EpiBF16Pair e{s_h, s_l, nullptr, 128 * 128, 128, 128};
    gemm2<false, EpiBF16Pair><<<dim3(1, 1, 32), 256, 0, stream>>>(g, e);
  }
  // ---- T_t[b][o][l'] = (S @ W_m)^T  (M=77p128, N=768, K=128; zero l'>=77)
  {
    GemmArgs g{}; g.Ah = s_h; g.Alo = s_l; g.Bh = wm_h; g.Blo = wm_l;
    g.K = 128; g.Mld = 128; g.Nld = 768; g.lda = 128; g.ldb = 128;
    g.sA = 128 * 128; g.sB = 0;
    EpiTransT e{tt_h, tt_l};
    gemm2<false, EpiTransT><<<dim3(6, 1, 32), 256, 0, stream>>>(g, e);
  }
  // ---- OUT: out[b][v][o] = P2t @ T_t + b_m  (M=1024, N=768, K=128)
  {
    GemmArgs g{}; g.Ah = p2t_h; g.Alo = p2t_l; g.Bh = tt_h; g.Blo = tt_l;
    g.K = 128; g.Mld = 1024; g.Nld = 768; g.lda = 128; g.ldb = 128;
    g.sA = 1024 * 128; g.sB = 768 * 128;
    EpiOutB e{(float*)d_out, b_m};
    gemm2<false, EpiOutB><<<dim3(6, 8, 32), 256, 0, stream>>>(g, e);
  }
  (void)in_sizes; (void)n_in; (void)out_size;
}

// Round 5
// 585.672 us; speedup vs baseline: 1.1369x; 1.0091x over previous
//
#include <hip/hip_runtime.h>

// ---------------------------------------------------------------------------
// DenseLanguageGuidanceModule on MI355X (gfx950)
// bf16 hi/lo split GEMMs (x3 MFMA, fp32 accumulate) for ~fp32 accuracy.
// Round 5: global_load_lds (width 16) staging for pre-split operands with
// linear-LDS-dest + source-XOR swizzle; 1 vmcnt(0)+barrier per K-step;
// XCD-aware block swizzle on the big projection GEMM.
// ---------------------------------------------------------------------------

using s16x8  = __attribute__((ext_vector_type(8))) short;
using f32x4v = __attribute__((ext_vector_type(4))) float;

__device__ __forceinline__ unsigned short f2bf(float f) {
  unsigned int u = __float_as_uint(f);
  u += 0x7fffu + ((u >> 16) & 1u);     // RNE
  return (unsigned short)(u >> 16);
}
__device__ __forceinline__ float bf2f(unsigned short h) {
  return __uint_as_float(((unsigned int)h) << 16);
}
__device__ __forceinline__ void split2(float v, unsigned short &hh, unsigned short &ll) {
  hh = f2bf(v);
  ll = f2bf(v - bf2f(hh));
}
__device__ __forceinline__ void split8v(float4 a, float4 b, s16x8& H, s16x8& L) {
  unsigned short hh, ll;
  split2(a.x, hh, ll); H[0] = (short)hh; L[0] = (short)ll;
  split2(a.y, hh, ll); H[1] = (short)hh; L[1] = (short)ll;
  split2(a.z, hh, ll); H[2] = (short)hh; L[2] = (short)ll;
  split2(a.w, hh, ll); H[3] = (short)hh; L[3] = (short)ll;
  split2(b.x, hh, ll); H[4] = (short)hh; L[4] = (short)ll;
  split2(b.y, hh, ll); H[5] = (short)hh; L[5] = (short)ll;
  split2(b.z, hh, ll); H[6] = (short)hh; L[6] = (short)ll;
  split2(b.w, hh, ll); H[7] = (short)hh; L[7] = (short)ll;
}

// async global->LDS, 16B per lane; LDS dest is wave-uniform base + lane*16
__device__ __forceinline__ void gload16(const unsigned short* g, unsigned short* l) {
  __builtin_amdgcn_global_load_lds(
      (const __attribute__((address_space(1))) unsigned int*)(const void*)g,
      (__attribute__((address_space(3))) unsigned int*)(void*)l,
      16, 0, 0);
}

// transpose W[K][N] -> Wt[N][Kpad] bf16 hi/lo, zero-pad k >= K
__global__ __launch_bounds__(256) void prep_weight(const float* __restrict__ W,
                                                   unsigned short* __restrict__ Wh,
                                                   unsigned short* __restrict__ Wl,
                                                   int K, int N, int Kpad) {
  __shared__ float tile[32][33];
  int nb = blockIdx.x * 32, kb = blockIdx.y * 32;
  int tx = threadIdx.x & 31, ty = threadIdx.x >> 5;   // 32 x 8
  #pragma unroll
  for (int i = 0; i < 32; i += 8) {
    int k = kb + ty + i, n = nb + tx;
    tile[ty + i][tx] = (k < K && n < N) ? W[(long)k * N + n] : 0.f;
  }
  __syncthreads();
  #pragma unroll
  for (int i = 0; i < 32; i += 8) {
    int n = nb + ty + i, k = kb + tx;
    if (n < N && k < Kpad) {
      unsigned short hh, ll;
      split2(tile[tx][ty + i], hh, ll);
      Wh[(long)n * Kpad + k] = hh;
      Wl[(long)n * Kpad + k] = ll;
    }
  }
}

// ---------------- generic NT GEMM, bf16 hi/lo x3, 2-phase dbuf ----------------
// C[m][n] = sum_k A[m][k] * Bt[n][k]
// Pre-split operands staged via global_load_lds (linear LDS, XOR on SOURCE
// chunk index); fp32 A (AF32) staged via regs + swizzled ds_write.
// Tile 128x128, BK=32, 256 threads (4 waves 2x2, wave=64x64 as 4x4 16x16x32).
// LDS: 2 bufs x (A pair 16KB + B pair 16KB) = 64KB. Chunk swizzle c^=((r>>1)&3).
struct GemmArgs {
  const unsigned short *Ah, *Alo, *Bh, *Blo;
  const float *Af;  // fp32 A source (when AF32)
  int K;            // multiple of 32
  int Mld, Nld;     // row clamp bounds
  int lda, ldb;     // row strides (elements)
  long long sA, sB; // batch strides (elements)
};

template <bool AF32, bool SWZ, class Epi>
__global__ __launch_bounds__(256, 2) void gemm2(GemmArgs g, Epi epi) {
  // shorts: buf p at p*16384; Ah +0, Al +4096, Bh +8192, Bl +12288
  __shared__ __align__(16) unsigned short sm[32768];

  int bidx = blockIdx.x, bidy = blockIdx.y;
  if constexpr (SWZ) {   // XCD-contiguous remap (requires nwg % 8 == 0)
    int nx = gridDim.x;
    int nwg = nx * gridDim.y;
    int orig = bidx + bidy * nx;
    int swz = (orig & 7) * (nwg >> 3) + (orig >> 3);
    bidx = swz % nx; bidy = swz / nx;
  }

  const int t    = threadIdx.x;
  const int b    = blockIdx.z;
  const int m0   = bidy * 128;
  const int n0   = bidx * 128;
  const int lane = t & 63;
  const int w    = t >> 6;
  const int wr   = (w >> 1) * 64;
  const int wc   = (w & 1) * 64;

  const long long aBase = (long long)b * g.sA;
  const long long bBase = (long long)b * g.sB;

  // ---- DMA staging coords (wave w covers local rows [w*32, w*32+32)) ----
  const int rw  = (w << 5) + (lane >> 2);          // local row, q=0 (q=1: +16)
  const int cl  = lane & 3;
  const int sck = ((cl ^ ((rw >> 1) & 3)) << 3);   // XOR'd source chunk (elems)
                                                    // note s(rw+16)==s(rw)
  int br0 = n0 + rw;      if (br0 > g.Nld - 1) br0 = g.Nld - 1;
  int br1 = n0 + rw + 16; if (br1 > g.Nld - 1) br1 = g.Nld - 1;
  const long long bR0d = bBase + (long long)br0 * g.ldb + sck;
  const long long bR1d = bBase + (long long)br1 * g.ldb + sck;
  int ar0 = m0 + rw;      if (ar0 > g.Mld - 1) ar0 = g.Mld - 1;
  int ar1 = m0 + rw + 16; if (ar1 > g.Mld - 1) ar1 = g.Mld - 1;
  const long long aR0d = aBase + (long long)ar0 * g.lda + sck;
  const long long aR1d = aBase + (long long)ar1 * g.lda + sck;
  const int dQ0 = w * 1024;        // LDS short-offset of wave's q=0 chunk
  const int dQ1 = w * 1024 + 512;  // q=1

  // ---- AF32 reg-staging coords (swizzled ds_write, as before) ----
  const int rA0 = t >> 2, rA1 = 64 + (t >> 2), cc = t & 3;
  const int cOff = cc << 3;
  int mr0 = m0 + rA0; if (mr0 > g.Mld - 1) mr0 = g.Mld - 1;
  int mr1 = m0 + rA1; if (mr1 > g.Mld - 1) mr1 = g.Mld - 1;
  const long long aR0 = aBase + (long long)mr0 * g.lda;
  const long long aR1 = aBase + (long long)mr1 * g.lda;
  const int wA0 = rA0 * 32 + ((cc ^ ((rA0 >> 1) & 3)) << 3);
  const int wA1 = rA1 * 32 + ((cc ^ ((rA1 >> 1) & 3)) << 3);

  // read-fragment offsets (constant; add buf base)
  int roffA[4], roffB[4];
  #pragma unroll
  for (int i = 0; i < 4; ++i) {
    int row = wr + i * 16 + (lane & 15);
    int ch  = lane >> 4;
    roffA[i] = row * 32 + ((ch ^ ((row >> 1) & 3)) << 3);
    row = wc + i * 16 + (lane & 15);
    roffB[i] = row * 32 + ((ch ^ ((row >> 1) & 3)) << 3);
  }

  f32x4v acc[4][4];
  #pragma unroll
  for (int i = 0; i < 4; ++i)
    #pragma unroll
    for (int j = 0; j < 4; ++j)
      #pragma unroll
      for (int r = 0; r < 4; ++r) acc[i][j][r] = 0.f;

  float4 pa0, pa1, pa2, pa3;   // AF32 prefetch regs

  auto issueDMA = [&](int k0, int p) {
    unsigned short* bb = sm + p * 16384;
    gload16(g.Bh  + (bR0d + k0), bb + 8192  + dQ0);
    gload16(g.Bh  + (bR1d + k0), bb + 8192  + dQ1);
    gload16(g.Blo + (bR0d + k0), bb + 12288 + dQ0);
    gload16(g.Blo + (bR1d + k0), bb + 12288 + dQ1);
    if constexpr (!AF32) {
      gload16(g.Ah  + (aR0d + k0), bb + dQ0);
      gload16(g.Ah  + (aR1d + k0), bb + dQ1);
      gload16(g.Alo + (aR0d + k0), bb + 4096 + dQ0);
      gload16(g.Alo + (aR1d + k0), bb + 4096 + dQ1);
    }
  };
  auto issueLoadsA = [&](int k0) {
    if constexpr (AF32) {
      const float* s0 = g.Af + (aR0 + k0 + cOff);
      const float* s1 = g.Af + (aR1 + k0 + cOff);
      pa0 = *(const float4*)s0; pa1 = *(const float4*)(s0 + 4);
      pa2 = *(const float4*)s1; pa3 = *(const float4*)(s1 + 4);
    }
  };
  auto writeStageA = [&](int p) {
    if constexpr (AF32) {
      unsigned short* base = sm + p * 16384;
      s16x8 H, L;
      split8v(pa0, pa1, H, L);
      *(s16x8*)(base + wA0) = H; *(s16x8*)(base + 4096 + wA0) = L;
      split8v(pa2, pa3, H, L);
      *(s16x8*)(base + wA1) = H; *(s16x8*)(base + 4096 + wA1) = L;
    }
  };

  // prologue: stage tile 0 into buf 0
  issueDMA(0, 0);
  issueLoadsA(0);
  writeStageA(0);
  int p = 0;
  const int nkt = g.K >> 5;
  for (int kt = 0; kt < nkt; ++kt) {
    asm volatile("s_waitcnt vmcnt(0)" ::: "memory");  // DMA for buf[p] done
    __syncthreads();                                  // all waves' DMA + A-writes visible
    if (kt + 1 < nkt) {
      issueDMA((kt + 1) << 5, p ^ 1);                 // flies under compute
      issueLoadsA((kt + 1) << 5);
    }
    unsigned short* base = sm + p * 16384;
    s16x8 ah[4], al[4], bh[4], bl[4];
    #pragma unroll
    for (int i = 0; i < 4; ++i) {
      ah[i] = *(const s16x8*)(base + roffA[i]);
      al[i] = *(const s16x8*)(base + 4096 + roffA[i]);
    }
    #pragma unroll
    for (int j = 0; j < 4; ++j) {
      bh[j] = *(const s16x8*)(base + 8192  + roffB[j]);
      bl[j] = *(const s16x8*)(base + 12288 + roffB[j]);
    }
    #pragma unroll
    for (int i = 0; i < 4; ++i)
      #pragma unroll
      for (int j = 0; j < 4; ++j) {
        acc[i][j] = __builtin_amdgcn_mfma_f32_16x16x32_bf16(ah[i], bh[j], acc[i][j], 0, 0, 0);
        acc[i][j] = __builtin_amdgcn_mfma_f32_16x16x32_bf16(ah[i], bl[j], acc[i][j], 0, 0, 0);
        acc[i][j] = __builtin_amdgcn_mfma_f32_16x16x32_bf16(al[i], bh[j], acc[i][j], 0, 0, 0);
      }
    if (kt + 1 < nkt) writeStageA(p ^ 1);   // regs arrived during compute
    p ^= 1;
  }
  // epilogue: D row=(lane>>4)*4+r, col=lane&15
  #pragma unroll
  for (int i = 0; i < 4; ++i)
    #pragma unroll
    for (int j = 0; j < 4; ++j) {
      int mm = m0 + wr + i * 16 + ((lane >> 4) << 2);
      int nn = n0 + wc + j * 16 + (lane & 15);
      epi(b, mm, nn, acc[i][j]);
    }
}

// ---------------- epilogues ----------------
struct EpiBF16Pair {   // out[b][m][n] bf16 hi/lo pair (+optional bias)
  unsigned short *h, *lo; const float* bias; long long bs; int ld; int Mst;
  __device__ void operator()(int b, int m, int n, f32x4v v) const {
    float bb = bias ? bias[n] : 0.f;
    #pragma unroll
    for (int r = 0; r < 4; ++r) {
      int mm = m + r;
      if (mm < Mst) {
        long long o = (long long)b * bs + (long long)mm * ld + n;
        unsigned short hh, ll;
        split2(v[r] + bb, hh, ll);
        h[o] = hh; lo[o] = ll;
      }
    }
  }
};

struct EpiDualL {      // K1f: n<512 -> fkl[m][n]; n>=512 -> fvl[m][n-512]
  unsigned short *kh, *kl, *vh, *vl; const float *bk, *bv;
  __device__ void operator()(int, int m, int n, f32x4v v) const {
    bool lo512 = n < 512;
    float bb = lo512 ? bk[n] : bv[n - 512];
    int nn = lo512 ? n : n - 512;
    unsigned short* H = lo512 ? kh : vh;
    unsigned short* L = lo512 ? kl : vl;
    #pragma unroll
    for (int r = 0; r < 4; ++r) {
      int mm = m + r;
      if (mm < 2464) {
        long long o = (long long)mm * 512 + nn;
        unsigned short hh, ll;
        split2(v[r] + bb, hh, ll);
        H[o] = hh; L[o] = ll;
      }
    }
  }
};

struct EpiDualV {      // K2f: n<512 -> fkv[m][n]; n>=512 -> fvvT[b2][n-512][v]
  unsigned short *kh, *kl, *vh, *vl; const float *bk, *bv;
  __device__ void operator()(int, int m, int n, f32x4v v) const {
    if (n < 512) {
      float bb = bk[n];
      #pragma unroll
      for (int r = 0; r < 4; ++r) {
        long long o = (long long)(m + r) * 512 + n;
        unsigned short hh, ll;
        split2(v[r] + bb, hh, ll);
        kh[o] = hh; kl[o] = ll;
      }
    } else {
      int b2 = m >> 10, vv = m & 1023;
      float bb = bv[n - 512];
      ushort4 H, L;
      split2(v[0] + bb, H.x, L.x); split2(v[1] + bb, H.y, L.y);
      split2(v[2] + bb, H.z, L.z); split2(v[3] + bb, H.w, L.w);
      long long o = ((long long)b2 * 512 + (n - 512)) * 1024 + vv;
      *(ushort4*)(vh + o) = H;
      *(ushort4*)(vl + o) = L;
    }
  }
};

struct EpiScore {      // K3: a_raw[b][m][n] fp32, scaled, m<77
  float* out;
  __device__ void operator()(int b, int m, int n, f32x4v v) const {
    #pragma unroll
    for (int r = 0; r < 4; ++r) {
      int mm = m + r;
      if (mm < 77)
        out[((long long)b * 77 + mm) * 1024 + n] = v[r] * 0.04419417382415922f;
    }
  }
};

struct EpiTransT {     // T-gemm: T_t[b][o=n][l=m+r], zero l>=77
  unsigned short *h, *lo;
  __device__ void operator()(int b, int m, int n, f32x4v v) const {
    #pragma unroll
    for (int r = 0; r < 4; ++r) {
      int mm = m + r;
      float val = (mm < 77) ? v[r] : 0.f;
      long long o = (long long)b * 98304 + (long long)n * 128 + mm;
      unsigned short hh, ll;
      split2(val, hh, ll);
      h[o] = hh; lo[o] = ll;
    }
  }
};

struct EpiOutB {       // OUT: d_out[b*1024+m][768] fp32 + b_m
  float* out; const float* bias;
  __device__ void operator()(int b, int m, int n, f32x4v v) const {
    float bb = bias[n];
    #pragma unroll
    for (int r = 0; r < 4; ++r)
      out[(long long)(b * 1024 + m + r) * 768 + n] = v[r] + bb;
  }
};

// ---------------- softmax over Nv (rows of a_raw) ----------------
__global__ __launch_bounds__(256) void softmax_rows(const float* __restrict__ a,
                                                    unsigned short* __restrict__ Ph,
                                                    unsigned short* __restrict__ Plo) {
  long row = blockIdx.x;                 // (b*77+l)
  const float* src = a + row * 1024;
  int t = threadIdx.x;
  float4 x = ((const float4*)src)[t];
  float mx = fmaxf(fmaxf(x.x, x.y), fmaxf(x.z, x.w));
  #pragma unroll
  for (int o = 32; o; o >>= 1) mx = fmaxf(mx, __shfl_xor(mx, o));
  __shared__ float red[4], red2[4];
  int w = t >> 6;
  if ((t & 63) == 0) red[w] = mx;
  __syncthreads();
  mx = fmaxf(fmaxf(red[0], red[1]), fmaxf(red[2], red[3]));
  float e0 = __expf(x.x - mx), e1 = __expf(x.y - mx);
  float e2 = __expf(x.z - mx), e3 = __expf(x.w - mx);
  float s = e0 + e1 + e2 + e3;
  #pragma unroll
  for (int o = 32; o; o >>= 1) s += __shfl_xor(s, o);
  if ((t & 63) == 0) red2[w] = s;
  __syncthreads();
  s = red2[0] + red2[1] + red2[2] + red2[3];
  float inv = 1.f / s;
  ushort4 H, L;
  split2(e0 * inv, H.x, L.x); split2(e1 * inv, H.y, L.y);
  split2(e2 * inv, H.z, L.z); split2(e3 * inv, H.w, L.w);
  long o = row * 1024 + (long)t * 4;
  *(ushort4*)(Ph + o)  = H;
  *(ushort4*)(Plo + o) = L;
}

// -------- softmax over Nl (cols), writes P2t[b][v][128] (k>=77 zero) --------
__global__ __launch_bounds__(128) void softmax_cols(const float* __restrict__ a,
                                                    unsigned short* __restrict__ Ph,
                                                    unsigned short* __restrict__ Plo) {
  __shared__ float tile[77 * 129];
  __shared__ float inv[128];
  int t = threadIdx.x;                  // 0..127
  int c = blockIdx.x;                   // v-chunk (of 128)
  int b = blockIdx.y;
  const float* src = a + (long)b * 77 * 1024 + c * 128;
  for (int r = 0; r < 77; ++r) tile[r * 129 + t] = src[(long)r * 1024 + t];
  __syncthreads();
  float mx = -1e30f;
  for (int r = 0; r < 77; ++r) mx = fmaxf(mx, tile[r * 129 + t]);
  float s = 0.f;
  for (int r = 0; r < 77; ++r) {
    float e = __expf(tile[r * 129 + t] - mx);
    tile[r * 129 + t] = e;
    s += e;
  }
  inv[t] = 1.f / s;
  __syncthreads();
  unsigned short* dh = Ph  + ((long)b * 1024 + c * 128) * 128;
  unsigned short* dl = Plo + ((long)b * 1024 + c * 128) * 128;
  for (int vb = 0; vb < 128; vb += 2) {
    int v = vb + (t >> 6);
    int k = (t & 63) * 2;
    float iv = inv[v];
    float p0 = (k     < 77) ? tile[k * 129 + v] * iv       : 0.f;
    float p1 = (k + 1 < 77) ? tile[(k + 1) * 129 + v] * iv : 0.f;
    ushort2 H, L;
    split2(p0, H.x, L.x); split2(p1, H.y, L.y);
    *(ushort2*)(dh + (long)v * 128 + k) = H;
    *(ushort2*)(dl + (long)v * 128 + k) = L;
  }
}

// ---------------------------------------------------------------------------
extern "C" void kernel_launch(void* const* d_in, const int* in_sizes, int n_in,
                              void* d_out, int out_size, void* d_ws, size_t ws_size,
                              hipStream_t stream) {
  const float* fv   = (const float*)d_in[0];
  const float* fl   = (const float*)d_in[1];
  const float* W_vk = (const float*)d_in[2];
  const float* b_vk = (const float*)d_in[3];
  const float* W_vv = (const float*)d_in[4];
  const float* b_vv = (const float*)d_in[5];
  const float* W_lk = (const float*)d_in[6];
  const float* b_lk = (const float*)d_in[7];
  const float* W_lv = (const float*)d_in[8];
  const float* b_lv = (const float*)d_in[9];
  const float* W_m  = (const float*)d_in[10];
  const float* b_m  = (const float*)d_in[11];

  char* base = (char*)d_ws;
  size_t off = 0;
  auto take = [&](size_t bytes) -> char* {
    char* p = base + off;
    off = (off + bytes + 255) & ~(size_t)255;
    return p;
  };

  // weights (concatenated, pre-transposed, bf16 pairs)
  unsigned short* wcatv_h = (unsigned short*)take(1572864);  // [1024][768]
  unsigned short* wcatv_l = (unsigned short*)take(1572864);
  unsigned short* wcatl_h = (unsigned short*)take(1048576);  // [1024][512]
  unsigned short* wcatl_l = (unsigned short*)take(1048576);
  unsigned short* wm_h    = (unsigned short*)take(196608);   // [768][128]
  unsigned short* wm_l    = (unsigned short*)take(196608);
  // intermediates
  unsigned short* fkl_h  = (unsigned short*)take(2523136);   // [2464][512]
  unsigned short* fkl_l  = (unsigned short*)take(2523136);
  unsigned short* fvl_h  = (unsigned short*)take(2523136);   // [2464][512]
  unsigned short* fvl_l  = (unsigned short*)take(2523136);
  unsigned short* fkv_h  = (unsigned short*)take(33554432);  // [32768][512]
  unsigned short* fkv_l  = (unsigned short*)take(33554432);
  unsigned short* fvvT_h = (unsigned short*)take(33554432);  // [32][512][1024]
  unsigned short* fvvT_l = (unsigned short*)take(33554432);
  float*          araw   = (float*)take(10092544);           // [32][77][1024]
  unsigned short* p1_h   = (unsigned short*)take(5046272);   // [2464][1024]
  unsigned short* p1_l   = (unsigned short*)take(5046272);
  unsigned short* p2t_h  = (unsigned short*)take(8388608);   // [32][1024][128]
  unsigned short* p2t_l  = (unsigned short*)take(8388608);
  unsigned short* fav_h  = (unsigned short*)take(4194304);   // [32][128][512]
  unsigned short* fav_l  = (unsigned short*)take(4194304);
  unsigned short* s_h    = (unsigned short*)take(1048576);   // [32][128][128]
  unsigned short* s_l    = (unsigned short*)take(1048576);
  unsigned short* tt_h   = (unsigned short*)take(6291456);   // [32][768][128]
  unsigned short* tt_l   = (unsigned short*)take(6291456);

  if (off > ws_size) return;  // workspace too small: fail loudly via mismatch

  // ---- prep weights ----
  prep_weight<<<dim3(16, 24), 256, 0, stream>>>(W_vk, wcatv_h, wcatv_l, 768, 512, 768);
  prep_weight<<<dim3(16, 24), 256, 0, stream>>>(W_vv, wcatv_h + 512 * 768, wcatv_l + 512 * 768, 768, 512, 768);
  prep_weight<<<dim3(16, 16), 256, 0, stream>>>(W_lk, wcatl_h, wcatl_l, 512, 512, 512);
  prep_weight<<<dim3(16, 16), 256, 0, stream>>>(W_lv, wcatl_h + 512 * 512, wcatl_l + 512 * 512, 512, 512, 512);
  prep_weight<<<dim3(24, 4), 256, 0, stream>>>(W_m, wm_h, wm_l, 77, 768, 128);

  // ---- K1f: [fk_l | fv_l] = fl @ [W_lk | W_lv] + bias  (M=2464, N=1024, K=512)
  {
    GemmArgs g{}; g.Af = fl; g.Bh = wcatl_h; g.Blo = wcatl_l;
    g.K = 512; g.Mld = 2464; g.Nld = 1024; g.lda = 512; g.ldb = 512; g.sA = 0; g.sB = 0;
    EpiDualL e{fkl_h, fkl_l, fvl_h, fvl_l, b_lk, b_lv};
    gemm2<true, false, EpiDualL><<<dim3(8, 20, 1), 256, 0, stream>>>(g, e);
  }
  // ---- K2f: [fk_v | fv_v^T] = fv @ [W_vk | W_vv] + bias (M=32768, N=1024, K=768)
  {
    GemmArgs g{}; g.Af = fv; g.Bh = wcatv_h; g.Blo = wcatv_l;
    g.K = 768; g.Mld = 32768; g.Nld = 1024; g.lda = 768; g.ldb = 768; g.sA = 0; g.sB = 0;
    EpiDualV e{fkv_h, fkv_l, fvvT_h, fvvT_l, b_vk, b_vv};
    gemm2<true, true, EpiDualV><<<dim3(8, 256, 1), 256, 0, stream>>>(g, e);
  }
  // ---- K3: a_raw[b][l][v] = fk_l . fk_v / sqrt(512) ----
  {
    GemmArgs g{}; g.Ah = fkl_h; g.Alo = fkl_l; g.Bh = fkv_h; g.Blo = fkv_l;
    g.K = 512; g.Mld = 77; g.Nld = 1024; g.lda = 512; g.ldb = 512;
    g.sA = 77 * 512; g.sB = 1024 * 512;
    EpiScore e{araw};
    gemm2<false, false, EpiScore><<<dim3(8, 1, 32), 256, 0, stream>>>(g, e);
  }
  // ---- softmaxes ----
  softmax_rows<<<2464, 256, 0, stream>>>(araw, p1_h, p1_l);
  softmax_cols<<<dim3(8, 32), 128, 0, stream>>>(araw, p2t_h, p2t_l);
  // ---- K5: fa_v[b][l][e] = P1 @ fv_v (via fv_vT)  (M=77p128, N=512, K=1024)
  {
    GemmArgs g{}; g.Ah = p1_h; g.Alo = p1_l; g.Bh = fvvT_h; g.Blo = fvvT_l;
    g.K = 1024; g.Mld = 77; g.Nld = 512; g.lda = 1024; g.ldb = 1024;
    g.sA = 77 * 1024; g.sB = 512 * 1024;
    EpiBF16Pair e{fav_h, fav_l, nullptr, 128 * 512, 512, 128};
    gemm2<false, false, EpiBF16Pair><<<dim3(4, 1, 32), 256, 0, stream>>>(g, e);
  }
  // ---- S[b][l'][l] = fv_l . fa_v  (M=77p128, N=128, K=512)
  {
    GemmArgs g{}; g.Ah = fvl_h; g.Alo = fvl_l; g.Bh = fav_h; g.Blo = fav_l;
    g.K = 512; g.Mld = 77; g.Nld = 128; g.lda = 512; g.ldb = 512;
    g.sA = 77 * 512; g.sB = 128 * 512;
    EpiBF16Pair e{s_h, s_l, nullptr, 128 * 128, 128, 128};
    gemm2<false, false, EpiBF16Pair><<<dim3(1, 1, 32), 256, 0, stream>>>(g, e);
  }
  // ---- T_t[b][o][l'] = (S @ W_m)^T  (M=77p128, N=768, K=128; zero l'>=77)
  {
    GemmArgs g{}; g.Ah = s_h; g.Alo = s_l; g.Bh = wm_h; g.Blo = wm_l;
    g.K = 128; g.Mld = 128; g.Nld = 768; g.lda = 128; g.ldb = 128;
    g.sA = 128 * 128; g.sB = 0;
    EpiTransT e{tt_h, tt_l};
    gemm2<false, false, EpiTransT><<<dim3(6, 1, 32), 256, 0, stream>>>(g, e);
  }
  // ---- OUT: out[b][v][o] = P2t @ T_t + b_m  (M=1024, N=768, K=128)
  {
    GemmArgs g{}; g.Ah = p2t_h; g.Alo = p2t_l; g.Bh = tt_h; g.Blo = tt_l;
    g.K = 128; g.Mld = 1024; g.Nld = 768; g.lda = 128; g.ldb = 128;
    g.sA = 1024 * 128; g.sB = 768 * 128;
    EpiOutB e{(float*)d_out, b_m};
    gemm2<false, false, EpiOutB><<<dim3(6, 8, 32), 256, 0, stream>>>(g, e);
  }
  (void)in_sizes; (void)n_in; (void)out_size;
}